// Round 13
// baseline (418.025 us; speedup 1.0000x reference)
//
#include <hip/hip_runtime.h>
#include <hip/hip_bf16.h>

// HyperbolicContrastiveLoss: N=8192, D=512, f32 in, scalar f32 out.
// loss = (1/2N) * sum_i [ log(sum_j exp(sim_ij)) + log(sum_i exp(sim_ij)) - 2*sim_ii ]
// exp(sim) = exp(-arccosh(arg)) = arg - sqrt(arg^2-1)  (exact).
// GEMM in fp8 e4m3, MX-scaled MFMA K=128 (scale=1.0): 128x128 tile, BK=128
// (4 K-steps), 8 waves (wave-out 64x32), double-buffered global_load_lds,
// XOR-swizzled LDS, 2 blocks/CU. The fp8 matrices are stored K-PERMUTED
// (pos g*32+ks*8 holds k=ks*32+g*8) so each lane's 32 operand bytes are
// contiguous -> 2x ds_read_b128, conflict-free. Dot products are invariant
// under a common k-permutation of both operands.

#define NROWS 8192
#define DDIM  512
#define BM 128
#define BN 128
#define BK 128            // fp8 elements per K-step
#define NT (DDIM / BK)    // 4 K-steps
#define LDSBUF 32768      // per-buffer bytes: A 16K | B 16K

typedef __attribute__((ext_vector_type(4))) float f32x4;
typedef __attribute__((ext_vector_type(4))) int   i32x4;
typedef __attribute__((ext_vector_type(8))) int   i32x8;

constexpr float EPSF = 1e-10f;
constexpr float DOT_SCALE = 1.0f / 1024.0f;   // undo 32x input scaling (32^2)

#define GLOAD_LDS16(g, l)                                                        \
    __builtin_amdgcn_global_load_lds(                                            \
        (const __attribute__((address_space(1))) void*)(g),                      \
        (__attribute__((address_space(3))) void*)(l), 16, 0, 0)

// f32 -> OCP e4m3fn with RNE (input pre-scaled; |f| < 240 guaranteed).
__device__ inline unsigned int f2e4m3(float f) {
    union { float f; unsigned int u; } x; x.f = f;
    unsigned int s = (x.u >> 24) & 0x80u;
    float af = __builtin_fabsf(f);
    unsigned int r;
    if (af >= 0.015625f) {                     // normal e4m3 range
        unsigned int m = x.u & 0x7fffffffu;
        m += 0x000fffffu + ((m >> 20) & 1u);   // RNE to 3 mantissa bits
        r = ((m >> 20) - (120u << 3)) & 0x7fu; // rebias 127->7
    } else {                                   // subnormal: multiples of 2^-9
        int q = (int)rintf(af * 512.0f);
        r = (unsigned int)q;
    }
    return r | s;
}

// One wave per row: convert audio+text row to fp8 (scaled by 32, K-PERMUTED
// layout), f32 row norms, f32-exact diagonal sim_ii. Blocks 0..31 also zero
// rowsum/colsum.
__global__ __launch_bounds__(256) void convert_norms(const float* __restrict__ audio,
                                                     const float* __restrict__ text,
                                                     unsigned char* __restrict__ Aq,
                                                     unsigned char* __restrict__ Bq,
                                                     float* __restrict__ a2,
                                                     float* __restrict__ b2,
                                                     float* __restrict__ diag,
                                                     float* __restrict__ zbuf) {
    if (blockIdx.x < 32) {
        int z = blockIdx.x * 512 + threadIdx.x * 2;
        *(float2*)(zbuf + z) = make_float2(0.f, 0.f);
    }
    int wave = threadIdx.x >> 6;
    int lane = threadIdx.x & 63;
    int row  = blockIdx.x * 4 + wave;
    const float* ra = audio + (size_t)row * DDIM + lane * 8;
    const float* rt = text  + (size_t)row * DDIM + lane * 8;
    float4 a0 = *(const float4*)(ra), a1 = *(const float4*)(ra + 4);
    float4 t0 = *(const float4*)(rt), t1 = *(const float4*)(rt + 4);

    float sa = a0.x*a0.x + a0.y*a0.y + a0.z*a0.z + a0.w*a0.w
             + a1.x*a1.x + a1.y*a1.y + a1.z*a1.z + a1.w*a1.w;
    float st = t0.x*t0.x + t0.y*t0.y + t0.z*t0.z + t0.w*t0.w
             + t1.x*t1.x + t1.y*t1.y + t1.z*t1.z + t1.w*t1.w;
    float dt = a0.x*t0.x + a0.y*t0.y + a0.z*t0.z + a0.w*t0.w
             + a1.x*t1.x + a1.y*t1.y + a1.z*t1.z + a1.w*t1.w;

    uint2 pa, pt;
    pa.x = f2e4m3(a0.x*32.f) | (f2e4m3(a0.y*32.f) << 8) |
           (f2e4m3(a0.z*32.f) << 16) | (f2e4m3(a0.w*32.f) << 24);
    pa.y = f2e4m3(a1.x*32.f) | (f2e4m3(a1.y*32.f) << 8) |
           (f2e4m3(a1.z*32.f) << 16) | (f2e4m3(a1.w*32.f) << 24);
    pt.x = f2e4m3(t0.x*32.f) | (f2e4m3(t0.y*32.f) << 8) |
           (f2e4m3(t0.z*32.f) << 16) | (f2e4m3(t0.w*32.f) << 24);
    pt.y = f2e4m3(t1.x*32.f) | (f2e4m3(t1.y*32.f) << 8) |
           (f2e4m3(t1.z*32.f) << 16) | (f2e4m3(t1.w*32.f) << 24);

    // K-permuted output position: lane holds k = lane*8..+8.
    // chunk c = lane>>4; g = lane&3; ks = (lane>>2)&3; pos = c*128+g*32+ks*8.
    {
        int c  = lane >> 4;
        int gq = lane & 3;
        int ks = (lane >> 2) & 3;
        size_t opos = (size_t)row * DDIM + c * 128 + gq * 32 + ks * 8;
        *(uint2*)(Aq + opos) = pa;
        *(uint2*)(Bq + opos) = pt;
    }

    #pragma unroll
    for (int m = 1; m < 64; m <<= 1) {
        sa += __shfl_xor(sa, m);
        st += __shfl_xor(st, m);
        dt += __shfl_xor(dt, m);
    }
    if (lane == 0) {
        a2[row] = sa;
        b2[row] = st;
        float a2c  = fminf(sa, 1.0f - EPSF);
        float b2c  = fminf(st, 1.0f - EPSF);
        float diff = sa + st - 2.0f * dt;
        float den  = fmaxf((1.0f - a2c) * (1.0f - b2c), EPSF);
        float arg  = fmaxf(1.0f + 2.0f * diff / den, 1.0f + EPSF);
        diag[row]  = -logf(arg + sqrtf(arg * arg - 1.0f));
    }
}

// 128x128 MFMA GEMM (A@B^T) in fp8, 8 waves (wm=w>>2, wn=w&3), wave-out 64x32.
// BK=128 -> 4 K-steps; 2-buffer prefetch-1 pipeline (R8-proven structure).
__global__ __launch_bounds__(512, 4) void hyper_gemm(
    const unsigned char* __restrict__ A, const unsigned char* __restrict__ B,
    const float* __restrict__ a2, const float* __restrict__ b2,
    float* __restrict__ rowsum, float* __restrict__ colsum) {

    __shared__ char lds[2 * LDSBUF];   // [buf][A 16K | B 16K]

    const int tid  = threadIdx.x;
    const int lane = tid & 63;
    const int w    = tid >> 6;         // 0..7
    const int wm   = w >> 2;           // 0..1
    const int wn   = w & 3;            // 0..3

    // XCD swizzle (round-5 proven): 8 consecutive dispatch slots on one XCD
    // share a B-panel with 8 different A-panels.
    const int bid = blockIdx.x;
    const int idx = bid >> 3;
    const int by  = (bid & 7) * 8 + (idx & 7);
    const int bx  = idx >> 3;
    const int i0 = by * BM;
    const int j0 = bx * BN;

    const int g  = lane >> 4;          // 0..3
    const int cl = lane & 15;          // 0..15

    // ---- staging: wave w stages rows [16w,16w+16) of A and B as 2 chunks of
    // 8 rows (64 lanes x 16B = 1KB/chunk, row = 128B). Linear LDS dest; global
    // 16B-chunk index pre-XOR'd by row&7 (rule #21; same XOR on reads).
    const int srow = lane >> 3;                    // 0..7 within chunk
    const int scol = (((lane & 7) ^ srow)) * 16;   // swizzled byte col
    const unsigned char* aP[2]; const unsigned char* bP[2]; int ldsOff[2];
    #pragma unroll
    for (int c = 0; c < 2; ++c) {
        int row = w * 16 + c * 8 + srow;
        aP[c] = A + (size_t)(i0 + row) * DDIM + scol;
        bP[c] = B + (size_t)(j0 + row) * DDIM + scol;
        ldsOff[c] = w * 2048 + c * 1024;
    }

    // ---- fragment ds_read_b128 byte offsets: lane (g,cl), frag row r:
    // 32 operand bytes at r*128 + [g*32, g*32+32), XOR-swizzled per 16B chunk.
    // addrX[..][h] = r*128 + ((g*32 + h*16) ^ ((r&7)<<4)); B at +16384.
    int addrA[4][2], addrB[2][2];
    #pragma unroll
    for (int mi = 0; mi < 4; ++mi) {
        int row = wm * 64 + mi * 16 + cl;
        int s = (row & 7) << 4;
        #pragma unroll
        for (int h = 0; h < 2; ++h)
            addrA[mi][h] = row * 128 + ((g * 32 + h * 16) ^ s);
    }
    #pragma unroll
    for (int ni = 0; ni < 2; ++ni) {
        int row = wn * 32 + ni * 16 + cl;
        int s = (row & 7) << 4;
        #pragma unroll
        for (int h = 0; h < 2; ++h)
            addrB[ni][h] = 16384 + row * 128 + ((g * 32 + h * 16) ^ s);
    }

    f32x4 acc[4][2];
    #pragma unroll
    for (int mi = 0; mi < 4; ++mi)
        #pragma unroll
        for (int ni = 0; ni < 2; ++ni)
            acc[mi][ni] = (f32x4)0.0f;

#define STAGE(buf, t)                                                     \
    do {                                                                  \
        _Pragma("unroll")                                                 \
        for (int c = 0; c < 2; ++c) {                                     \
            GLOAD_LDS16(aP[c] + (t) * BK,                                 \
                        lds + (buf) * LDSBUF + ldsOff[c]);                \
            GLOAD_LDS16(bP[c] + (t) * BK,                                 \
                        lds + (buf) * LDSBUF + 16384 + ldsOff[c]);        \
        }                                                                 \
    } while (0)

#if __has_builtin(__builtin_amdgcn_mfma_scale_f32_16x16x128_f8f6f4)
#define COMPUTE(buf)                                                      \
    do {                                                                  \
        i32x8 av[4], bv[2];                                               \
        _Pragma("unroll")                                                 \
        for (int mi = 0; mi < 4; ++mi) {                                  \
            i32x4 lo = *(const i32x4*)(lds + (buf) * LDSBUF + addrA[mi][0]); \
            i32x4 hi = *(const i32x4*)(lds + (buf) * LDSBUF + addrA[mi][1]); \
            av[mi][0]=lo[0]; av[mi][1]=lo[1]; av[mi][2]=lo[2]; av[mi][3]=lo[3]; \
            av[mi][4]=hi[0]; av[mi][5]=hi[1]; av[mi][6]=hi[2]; av[mi][7]=hi[3]; \
        }                                                                 \
        _Pragma("unroll")                                                 \
        for (int ni = 0; ni < 2; ++ni) {                                  \
            i32x4 lo = *(const i32x4*)(lds + (buf) * LDSBUF + addrB[ni][0]); \
            i32x4 hi = *(const i32x4*)(lds + (buf) * LDSBUF + addrB[ni][1]); \
            bv[ni][0]=lo[0]; bv[ni][1]=lo[1]; bv[ni][2]=lo[2]; bv[ni][3]=lo[3]; \
            bv[ni][4]=hi[0]; bv[ni][5]=hi[1]; bv[ni][6]=hi[2]; bv[ni][7]=hi[3]; \
        }                                                                 \
        _Pragma("unroll")                                                 \
        for (int mi = 0; mi < 4; ++mi)                                    \
            _Pragma("unroll")                                             \
            for (int ni = 0; ni < 2; ++ni)                                \
                acc[mi][ni] = __builtin_amdgcn_mfma_scale_f32_16x16x128_f8f6f4( \
                    av[mi], bv[ni], acc[mi][ni], 0, 0, 0, 127, 0, 127);   \
    } while (0)
#else
// Fallback: 4x non-scaled 16x16x32 fp8 over the same permuted layout.
// b64 at addrX[..][ks>>1] + (ks&1)*8 (XOR is 16B-granular; +8 is safe).
#define COMPUTE(buf)                                                      \
    do {                                                                  \
        _Pragma("unroll")                                                 \
        for (int ks = 0; ks < 4; ++ks) {                                  \
            long av[4]; long bv[2];                                       \
            _Pragma("unroll")                                             \
            for (int mi = 0; mi < 4; ++mi)                                \
                av[mi] = *(const long*)(lds + (buf) * LDSBUF              \
                          + addrA[mi][ks >> 1] + (ks & 1) * 8);           \
            _Pragma("unroll")                                             \
            for (int ni = 0; ni < 2; ++ni)                                \
                bv[ni] = *(const long*)(lds + (buf) * LDSBUF              \
                          + addrB[ni][ks >> 1] + (ks & 1) * 8);           \
            _Pragma("unroll")                                             \
            for (int mi = 0; mi < 4; ++mi)                                \
                _Pragma("unroll")                                         \
                for (int ni = 0; ni < 2; ++ni)                            \
                    acc[mi][ni] = __builtin_amdgcn_mfma_f32_16x16x32_fp8_fp8( \
                        av[mi], bv[ni], acc[mi][ni], 0, 0, 0);            \
        }                                                                 \
    } while (0)
#endif

    STAGE(0, 0);
    __syncthreads();                       // tile 0 resident
    #pragma unroll
    for (int t = 0; t < NT; ++t) {
        if (t + 1 < NT) STAGE((t + 1) & 1, t + 1);   // prefetch next tile
        COMPUTE(t & 1);
        if (t + 1 < NT) __syncthreads();   // drains prefetch + lds reads
    }
#undef STAGE
#undef COMPUTE

    // ---- epilogue: e = arg - sqrt(arg^2-1); accumulate row/col partials.
    float B2c[2], fb[2];
    #pragma unroll
    for (int ni = 0; ni < 2; ++ni) {
        float B2 = b2[j0 + wn * 32 + ni * 16 + cl];
        B2c[ni] = B2;
        fb[ni] = __builtin_amdgcn_rcpf(1.0f - fminf(B2, 1.0f - EPSF));
    }

    float cp[2] = {0.f, 0.f};
    #pragma unroll
    for (int mi = 0; mi < 4; ++mi) {
        #pragma unroll
        for (int reg = 0; reg < 4; ++reg) {
            int   gi  = i0 + wm * 64 + mi * 16 + g * 4 + reg;
            float A2  = a2[gi];
            float fa  = 2.0f * __builtin_amdgcn_rcpf(1.0f - fminf(A2, 1.0f - EPSF));
            float rsum = 0.f;
            #pragma unroll
            for (int ni = 0; ni < 2; ++ni) {
                float dot  = acc[mi][ni][reg];
                float diff = fmaf(-2.0f * DOT_SCALE, dot, A2 + B2c[ni]);
                float arg  = fmaf(diff * fa, fb[ni], 1.0f);
                arg = fmaxf(arg, 1.0f);
                float sq = sqrtf(fmaf(arg, arg, -1.0f));
                float e  = arg - sq;      // exp(-arccosh(arg)), exact
                rsum += e;
                cp[ni] += e;
            }
            float v = rsum;
            v += __shfl_xor(v, 1); v += __shfl_xor(v, 2);
            v += __shfl_xor(v, 4); v += __shfl_xor(v, 8);
            if (cl == 0) atomicAdd(&rowsum[gi], v);
        }
    }
    #pragma unroll
    for (int ni = 0; ni < 2; ++ni) {
        float v = cp[ni];
        v += __shfl_xor(v, 16); v += __shfl_xor(v, 32);
        if (g == 0) atomicAdd(&colsum[j0 + wn * 32 + ni * 16 + cl], v);
    }
}

// Single block, direct write to out[0].
__global__ __launch_bounds__(1024) void finalize(const float* __restrict__ rowsum,
                                                 const float* __restrict__ colsum,
                                                 const float* __restrict__ diag,
                                                 float* __restrict__ out) {
    float s = 0.f;
    for (int i = threadIdx.x; i < NROWS; i += 1024)
        s += logf(rowsum[i]) + logf(colsum[i]) - 2.0f * diag[i];
    __shared__ float red[16];
    int lane = threadIdx.x & 63, wv = threadIdx.x >> 6;
    #pragma unroll
    for (int m = 1; m < 64; m <<= 1) s += __shfl_xor(s, m);
    if (lane == 0) red[wv] = s;
    __syncthreads();
    if (threadIdx.x == 0) {
        float t = 0.f;
        #pragma unroll
        for (int k = 0; k < 16; ++k) t += red[k];
        out[0] = t / (2.0f * NROWS);
    }
}

extern "C" void kernel_launch(void* const* d_in, const int* in_sizes, int n_in,
                              void* d_out, int out_size, void* d_ws, size_t ws_size,
                              hipStream_t stream) {
    const float* audio = (const float*)d_in[0];
    const float* text  = (const float*)d_in[1];
    // labels (d_in[2]) are arange(N) -> diagonal; not needed.
    float* out = (float*)d_out;

    char* ws = (char*)d_ws;
    const size_t BF = (size_t)NROWS * DDIM;   // 4 MiB per fp8 matrix
    unsigned char* Aq = (unsigned char*)ws;
    unsigned char* Bq = (unsigned char*)(ws + BF);
    float* a2     = (float*)(ws + 2 * BF);
    float* b2     = a2 + NROWS;
    float* rowsum = b2 + NROWS;
    float* colsum = rowsum + NROWS;
    float* diag   = colsum + NROWS;

    convert_norms<<<NROWS / 4, 256, 0, stream>>>(audio, text, Aq, Bq, a2, b2, diag, rowsum);
    hyper_gemm<<<(NROWS / BM) * (NROWS / BN), 512, 0, stream>>>(Aq, Bq, a2, b2, rowsum, colsum);
    finalize<<<1, 1024, 0, stream>>>(rowsum, colsum, diag, out);
}

// Round 14
// 202.995 us; speedup vs baseline: 2.0593x; 2.0593x over previous
//
#include <hip/hip_runtime.h>
#include <hip/hip_bf16.h>

// HyperbolicContrastiveLoss: N=8192, D=512, f32 in, scalar f32 out.
// loss = (1/2N) * sum_i [ log(sum_j exp(sim_ij)) + log(sum_i exp(sim_ij)) - 2*sim_ii ]
// exp(sim) = exp(-arccosh(arg)) = arg - sqrt(arg^2-1)  (exact).
// GEMM in fp8 e4m3 (non-scaled 16x16x32 MFMA): 128x128 tile, BK=128 (4 K-steps),
// 8 waves (wave-out 64x32), double-buffered global_load_lds, XOR-swizzled LDS,
// 2 blocks/CU. A/B stored K-PERMUTED (pos g*32+ks*8 holds k=ks*32+g*8) so each
// lane's 4 k-slices are 32 contiguous bytes -> 2x ds_read_b128 per fragment,
// bank-balanced (8 accesses/bank). Dot products invariant under a common
// k-permutation of both operands (layout proven correct in R13).

#define NROWS 8192
#define DDIM  512
#define BM 128
#define BN 128
#define BK 128            // fp8 elements per K-step
#define NT (DDIM / BK)    // 4 K-steps
#define LDSBUF 32768      // per-buffer bytes: A 16K | B 16K

typedef __attribute__((ext_vector_type(4))) float f32x4;
typedef __attribute__((ext_vector_type(2))) long  i64x2;

constexpr float EPSF = 1e-10f;
constexpr float DOT_SCALE = 1.0f / 1024.0f;   // undo 32x input scaling (32^2)

#define GLOAD_LDS16(g, l)                                                        \
    __builtin_amdgcn_global_load_lds(                                            \
        (const __attribute__((address_space(1))) void*)(g),                      \
        (__attribute__((address_space(3))) void*)(l), 16, 0, 0)

// f32 -> OCP e4m3fn with RNE (input pre-scaled; |f| < 240 guaranteed).
__device__ inline unsigned int f2e4m3(float f) {
    union { float f; unsigned int u; } x; x.f = f;
    unsigned int s = (x.u >> 24) & 0x80u;
    float af = __builtin_fabsf(f);
    unsigned int r;
    if (af >= 0.015625f) {                     // normal e4m3 range
        unsigned int m = x.u & 0x7fffffffu;
        m += 0x000fffffu + ((m >> 20) & 1u);   // RNE to 3 mantissa bits
        r = ((m >> 20) - (120u << 3)) & 0x7fu; // rebias 127->7
    } else {                                   // subnormal: multiples of 2^-9
        int q = (int)rintf(af * 512.0f);
        r = (unsigned int)q;
    }
    return r | s;
}

// One wave per row: convert audio+text row to fp8 (scaled by 32, K-PERMUTED
// layout), f32 row norms, f32-exact diagonal sim_ii. Blocks 0..31 also zero
// rowsum/colsum.
__global__ __launch_bounds__(256) void convert_norms(const float* __restrict__ audio,
                                                     const float* __restrict__ text,
                                                     unsigned char* __restrict__ Aq,
                                                     unsigned char* __restrict__ Bq,
                                                     float* __restrict__ a2,
                                                     float* __restrict__ b2,
                                                     float* __restrict__ diag,
                                                     float* __restrict__ zbuf) {
    if (blockIdx.x < 32) {
        int z = blockIdx.x * 512 + threadIdx.x * 2;
        *(float2*)(zbuf + z) = make_float2(0.f, 0.f);
    }
    int wave = threadIdx.x >> 6;
    int lane = threadIdx.x & 63;
    int row  = blockIdx.x * 4 + wave;
    const float* ra = audio + (size_t)row * DDIM + lane * 8;
    const float* rt = text  + (size_t)row * DDIM + lane * 8;
    float4 a0 = *(const float4*)(ra), a1 = *(const float4*)(ra + 4);
    float4 t0 = *(const float4*)(rt), t1 = *(const float4*)(rt + 4);

    float sa = a0.x*a0.x + a0.y*a0.y + a0.z*a0.z + a0.w*a0.w
             + a1.x*a1.x + a1.y*a1.y + a1.z*a1.z + a1.w*a1.w;
    float st = t0.x*t0.x + t0.y*t0.y + t0.z*t0.z + t0.w*t0.w
             + t1.x*t1.x + t1.y*t1.y + t1.z*t1.z + t1.w*t1.w;
    float dt = a0.x*t0.x + a0.y*t0.y + a0.z*t0.z + a0.w*t0.w
             + a1.x*t1.x + a1.y*t1.y + a1.z*t1.z + a1.w*t1.w;

    uint2 pa, pt;
    pa.x = f2e4m3(a0.x*32.f) | (f2e4m3(a0.y*32.f) << 8) |
           (f2e4m3(a0.z*32.f) << 16) | (f2e4m3(a0.w*32.f) << 24);
    pa.y = f2e4m3(a1.x*32.f) | (f2e4m3(a1.y*32.f) << 8) |
           (f2e4m3(a1.z*32.f) << 16) | (f2e4m3(a1.w*32.f) << 24);
    pt.x = f2e4m3(t0.x*32.f) | (f2e4m3(t0.y*32.f) << 8) |
           (f2e4m3(t0.z*32.f) << 16) | (f2e4m3(t0.w*32.f) << 24);
    pt.y = f2e4m3(t1.x*32.f) | (f2e4m3(t1.y*32.f) << 8) |
           (f2e4m3(t1.z*32.f) << 16) | (f2e4m3(t1.w*32.f) << 24);

    // K-permuted output position: lane holds k = lane*8..+8.
    // chunk c = lane>>4; g = lane&3; ks = (lane>>2)&3; pos = c*128+g*32+ks*8.
    {
        int c  = lane >> 4;
        int gq = lane & 3;
        int ks = (lane >> 2) & 3;
        size_t opos = (size_t)row * DDIM + c * 128 + gq * 32 + ks * 8;
        *(uint2*)(Aq + opos) = pa;
        *(uint2*)(Bq + opos) = pt;
    }

    #pragma unroll
    for (int m = 1; m < 64; m <<= 1) {
        sa += __shfl_xor(sa, m);
        st += __shfl_xor(st, m);
        dt += __shfl_xor(dt, m);
    }
    if (lane == 0) {
        a2[row] = sa;
        b2[row] = st;
        float a2c  = fminf(sa, 1.0f - EPSF);
        float b2c  = fminf(st, 1.0f - EPSF);
        float diff = sa + st - 2.0f * dt;
        float den  = fmaxf((1.0f - a2c) * (1.0f - b2c), EPSF);
        float arg  = fmaxf(1.0f + 2.0f * diff / den, 1.0f + EPSF);
        diag[row]  = -logf(arg + sqrtf(arg * arg - 1.0f));
    }
}

// 128x128 MFMA GEMM (A@B^T) in fp8, 8 waves (wm=w>>2, wn=w&3), wave-out 64x32.
// BK=128 -> 4 K-steps; 2-buffer prefetch-1 pipeline (R8-proven structure).
__global__ __launch_bounds__(512, 4) void hyper_gemm(
    const unsigned char* __restrict__ A, const unsigned char* __restrict__ B,
    const float* __restrict__ a2, const float* __restrict__ b2,
    float* __restrict__ rowsum, float* __restrict__ colsum) {

    __shared__ char lds[2 * LDSBUF];   // [buf][A 16K | B 16K]

    const int tid  = threadIdx.x;
    const int lane = tid & 63;
    const int w    = tid >> 6;         // 0..7
    const int wm   = w >> 2;           // 0..1
    const int wn   = w & 3;            // 0..3

    // XCD swizzle (round-5 proven): 8 consecutive dispatch slots on one XCD
    // share a B-panel with 8 different A-panels.
    const int bid = blockIdx.x;
    const int idx = bid >> 3;
    const int by  = (bid & 7) * 8 + (idx & 7);
    const int bx  = idx >> 3;
    const int i0 = by * BM;
    const int j0 = bx * BN;

    const int g  = lane >> 4;          // 0..3
    const int cl = lane & 15;          // 0..15

    // ---- staging: wave w stages rows [16w,16w+16) of A and B as 2 chunks of
    // 8 rows (64 lanes x 16B = 1KB/chunk, row = 128B). Linear LDS dest; global
    // 16B-chunk index pre-XOR'd by row&7 (rule #21; same XOR on reads).
    const int srow = lane >> 3;                    // 0..7 within chunk
    const int scol = (((lane & 7) ^ srow)) * 16;   // swizzled byte col
    const unsigned char* aP[2]; const unsigned char* bP[2]; int ldsOff[2];
    #pragma unroll
    for (int c = 0; c < 2; ++c) {
        int row = w * 16 + c * 8 + srow;
        aP[c] = A + (size_t)(i0 + row) * DDIM + scol;
        bP[c] = B + (size_t)(j0 + row) * DDIM + scol;
        ldsOff[c] = w * 2048 + c * 1024;
    }

    // ---- fragment ds_read_b128 byte offsets: lane (g,cl), frag row r:
    // 32 operand bytes at r*128 + [g*32, g*32+32), XOR-swizzled per 16B chunk.
    // addrX[..][h] = r*128 + ((g*32 + h*16) ^ ((r&7)<<4)); B at +16384.
    // Half h covers k-slices ks = 2h (bytes 0-8) and 2h+1 (bytes 8-16).
    int addrA[4][2], addrB[2][2];
    #pragma unroll
    for (int mi = 0; mi < 4; ++mi) {
        int row = wm * 64 + mi * 16 + cl;
        int s = (row & 7) << 4;
        #pragma unroll
        for (int h = 0; h < 2; ++h)
            addrA[mi][h] = row * 128 + ((g * 32 + h * 16) ^ s);
    }
    #pragma unroll
    for (int ni = 0; ni < 2; ++ni) {
        int row = wn * 32 + ni * 16 + cl;
        int s = (row & 7) << 4;
        #pragma unroll
        for (int h = 0; h < 2; ++h)
            addrB[ni][h] = 16384 + row * 128 + ((g * 32 + h * 16) ^ s);
    }

    f32x4 acc[4][2];
    #pragma unroll
    for (int mi = 0; mi < 4; ++mi)
        #pragma unroll
        for (int ni = 0; ni < 2; ++ni)
            acc[mi][ni] = (f32x4)0.0f;

#define STAGE(buf, t)                                                     \
    do {                                                                  \
        _Pragma("unroll")                                                 \
        for (int c = 0; c < 2; ++c) {                                     \
            GLOAD_LDS16(aP[c] + (t) * BK,                                 \
                        lds + (buf) * LDSBUF + ldsOff[c]);                \
            GLOAD_LDS16(bP[c] + (t) * BK,                                 \
                        lds + (buf) * LDSBUF + 16384 + ldsOff[c]);        \
        }                                                                 \
    } while (0)

// Per half h: one ds_read_b128 per fragment-row (i64x2), whose two longs are
// the MFMA operands for k-slices 2h and 2h+1. All indices static -> registers.
#define COMPUTE(buf)                                                      \
    do {                                                                  \
        _Pragma("unroll")                                                 \
        for (int h = 0; h < 2; ++h) {                                     \
            i64x2 va[4], vb[2];                                           \
            _Pragma("unroll")                                             \
            for (int mi = 0; mi < 4; ++mi)                                \
                va[mi] = *(const i64x2*)(lds + (buf) * LDSBUF + addrA[mi][h]); \
            _Pragma("unroll")                                             \
            for (int ni = 0; ni < 2; ++ni)                                \
                vb[ni] = *(const i64x2*)(lds + (buf) * LDSBUF + addrB[ni][h]); \
            _Pragma("unroll")                                             \
            for (int half = 0; half < 2; ++half)                          \
                _Pragma("unroll")                                         \
                for (int mi = 0; mi < 4; ++mi)                            \
                    _Pragma("unroll")                                     \
                    for (int ni = 0; ni < 2; ++ni)                        \
                        acc[mi][ni] = __builtin_amdgcn_mfma_f32_16x16x32_fp8_fp8( \
                            va[mi][half], vb[ni][half], acc[mi][ni], 0, 0, 0);    \
        }                                                                 \
    } while (0)

    STAGE(0, 0);
    __syncthreads();                       // tile 0 resident
    #pragma unroll
    for (int t = 0; t < NT; ++t) {
        if (t + 1 < NT) STAGE((t + 1) & 1, t + 1);   // prefetch next tile
        COMPUTE(t & 1);
        if (t + 1 < NT) __syncthreads();   // drains prefetch + lds reads
    }
#undef STAGE
#undef COMPUTE

    // ---- epilogue: e = arg - sqrt(arg^2-1); accumulate row/col partials.
    float B2c[2], fb[2];
    #pragma unroll
    for (int ni = 0; ni < 2; ++ni) {
        float B2 = b2[j0 + wn * 32 + ni * 16 + cl];
        B2c[ni] = B2;
        fb[ni] = __builtin_amdgcn_rcpf(1.0f - fminf(B2, 1.0f - EPSF));
    }

    float cp[2] = {0.f, 0.f};
    #pragma unroll
    for (int mi = 0; mi < 4; ++mi) {
        #pragma unroll
        for (int reg = 0; reg < 4; ++reg) {
            int   gi  = i0 + wm * 64 + mi * 16 + g * 4 + reg;
            float A2  = a2[gi];
            float fa  = 2.0f * __builtin_amdgcn_rcpf(1.0f - fminf(A2, 1.0f - EPSF));
            float rsum = 0.f;
            #pragma unroll
            for (int ni = 0; ni < 2; ++ni) {
                float dot  = acc[mi][ni][reg];
                float diff = fmaf(-2.0f * DOT_SCALE, dot, A2 + B2c[ni]);
                float arg  = fmaf(diff * fa, fb[ni], 1.0f);
                arg = fmaxf(arg, 1.0f);
                float sq = sqrtf(fmaf(arg, arg, -1.0f));
                float e  = arg - sq;      // exp(-arccosh(arg)), exact
                rsum += e;
                cp[ni] += e;
            }
            float v = rsum;
            v += __shfl_xor(v, 1); v += __shfl_xor(v, 2);
            v += __shfl_xor(v, 4); v += __shfl_xor(v, 8);
            if (cl == 0) atomicAdd(&rowsum[gi], v);
        }
    }
    #pragma unroll
    for (int ni = 0; ni < 2; ++ni) {
        float v = cp[ni];
        v += __shfl_xor(v, 16); v += __shfl_xor(v, 32);
        if (g == 0) atomicAdd(&colsum[j0 + wn * 32 + ni * 16 + cl], v);
    }
}

// Single block, direct write to out[0].
__global__ __launch_bounds__(1024) void finalize(const float* __restrict__ rowsum,
                                                 const float* __restrict__ colsum,
                                                 const float* __restrict__ diag,
                                                 float* __restrict__ out) {
    float s = 0.f;
    for (int i = threadIdx.x; i < NROWS; i += 1024)
        s += logf(rowsum[i]) + logf(colsum[i]) - 2.0f * diag[i];
    __shared__ float red[16];
    int lane = threadIdx.x & 63, wv = threadIdx.x >> 6;
    #pragma unroll
    for (int m = 1; m < 64; m <<= 1) s += __shfl_xor(s, m);
    if (lane == 0) red[wv] = s;
    __syncthreads();
    if (threadIdx.x == 0) {
        float t = 0.f;
        #pragma unroll
        for (int k = 0; k < 16; ++k) t += red[k];
        out[0] = t / (2.0f * NROWS);
    }
}

extern "C" void kernel_launch(void* const* d_in, const int* in_sizes, int n_in,
                              void* d_out, int out_size, void* d_ws, size_t ws_size,
                              hipStream_t stream) {
    const float* audio = (const float*)d_in[0];
    const float* text  = (const float*)d_in[1];
    // labels (d_in[2]) are arange(N) -> diagonal; not needed.
    float* out = (float*)d_out;

    char* ws = (char*)d_ws;
    const size_t BF = (size_t)NROWS * DDIM;   // 4 MiB per fp8 matrix
    unsigned char* Aq = (unsigned char*)ws;
    unsigned char* Bq = (unsigned char*)(ws + BF);
    float* a2     = (float*)(ws + 2 * BF);
    float* b2     = a2 + NROWS;
    float* rowsum = b2 + NROWS;
    float* colsum = rowsum + NROWS;
    float* diag   = colsum + NROWS;

    convert_norms<<<NROWS / 4, 256, 0, stream>>>(audio, text, Aq, Bq, a2, b2, diag, rowsum);
    hyper_gemm<<<(NROWS / BM) * (NROWS / BN), 512, 0, stream>>>(Aq, Bq, a2, b2, rowsum, colsum);
    finalize<<<1, 1024, 0, stream>>>(rowsum, colsum, diag, out);
}

// Round 15
// 201.374 us; speedup vs baseline: 2.0759x; 1.0080x over previous
//
#include <hip/hip_runtime.h>
#include <hip/hip_bf16.h>

// HyperbolicContrastiveLoss: N=8192, D=512, f32 in, scalar f32 out.
// loss = (1/2N) * sum_i [ log(sum_j exp(sim_ij)) + log(sum_i exp(sim_ij)) - 2*sim_ii ]
// exp(sim) = exp(-arccosh(arg)) = arg - sqrt(arg^2-1)  (exact).
// GEMM in fp8 e4m3 (non-scaled 16x16x32 MFMA): 128x128 tile, BK=128 (4 K-steps),
// 8 waves (wave-out 64x32), double-buffered global_load_lds, 2 blocks/CU.
// A/B stored K-PERMUTED (pos g*32+ks*8 holds k=ks*32+g*8): 2x ds_read_b128/frag.
// LDS swizzle: chunk = lanechunk ^ (row&7) ^ (((row>>3)&1)<<2)  -- the bit-3 term
// breaks the cl/cl+8 same-bank-group collision (R14: 4 conflict cyc per read).

#define NROWS 8192
#define DDIM  512
#define BM 128
#define BN 128
#define BK 128            // fp8 elements per K-step
#define NT (DDIM / BK)    // 4 K-steps
#define LDSBUF 32768      // per-buffer bytes: A 16K | B 16K

typedef __attribute__((ext_vector_type(4))) float f32x4;
typedef __attribute__((ext_vector_type(2))) long  i64x2;

constexpr float EPSF = 1e-10f;
constexpr float DOT_SCALE = 1.0f / 1024.0f;   // undo 32x input scaling (32^2)

#define GLOAD_LDS16(g, l)                                                        \
    __builtin_amdgcn_global_load_lds(                                            \
        (const __attribute__((address_space(1))) void*)(g),                      \
        (__attribute__((address_space(3))) void*)(l), 16, 0, 0)

// f32 -> OCP e4m3fn with RNE (input pre-scaled; |f| < 240 guaranteed).
__device__ inline unsigned int f2e4m3(float f) {
    union { float f; unsigned int u; } x; x.f = f;
    unsigned int s = (x.u >> 24) & 0x80u;
    float af = __builtin_fabsf(f);
    unsigned int r;
    if (af >= 0.015625f) {                     // normal e4m3 range
        unsigned int m = x.u & 0x7fffffffu;
        m += 0x000fffffu + ((m >> 20) & 1u);   // RNE to 3 mantissa bits
        r = ((m >> 20) - (120u << 3)) & 0x7fu; // rebias 127->7
    } else {                                   // subnormal: multiples of 2^-9
        int q = (int)rintf(af * 512.0f);
        r = (unsigned int)q;
    }
    return r | s;
}

// One wave per row: convert audio+text row to fp8 (scaled by 32, K-PERMUTED
// layout), f32 row norms, f32-exact diagonal sim_ii. Blocks 0..31 also zero
// rowsum/colsum.
__global__ __launch_bounds__(256) void convert_norms(const float* __restrict__ audio,
                                                     const float* __restrict__ text,
                                                     unsigned char* __restrict__ Aq,
                                                     unsigned char* __restrict__ Bq,
                                                     float* __restrict__ a2,
                                                     float* __restrict__ b2,
                                                     float* __restrict__ diag,
                                                     float* __restrict__ zbuf) {
    if (blockIdx.x < 32) {
        int z = blockIdx.x * 512 + threadIdx.x * 2;
        *(float2*)(zbuf + z) = make_float2(0.f, 0.f);
    }
    int wave = threadIdx.x >> 6;
    int lane = threadIdx.x & 63;
    int row  = blockIdx.x * 4 + wave;
    const float* ra = audio + (size_t)row * DDIM + lane * 8;
    const float* rt = text  + (size_t)row * DDIM + lane * 8;
    float4 a0 = *(const float4*)(ra), a1 = *(const float4*)(ra + 4);
    float4 t0 = *(const float4*)(rt), t1 = *(const float4*)(rt + 4);

    float sa = a0.x*a0.x + a0.y*a0.y + a0.z*a0.z + a0.w*a0.w
             + a1.x*a1.x + a1.y*a1.y + a1.z*a1.z + a1.w*a1.w;
    float st = t0.x*t0.x + t0.y*t0.y + t0.z*t0.z + t0.w*t0.w
             + t1.x*t1.x + t1.y*t1.y + t1.z*t1.z + t1.w*t1.w;
    float dt = a0.x*t0.x + a0.y*t0.y + a0.z*t0.z + a0.w*t0.w
             + a1.x*t1.x + a1.y*t1.y + a1.z*t1.z + a1.w*t1.w;

    uint2 pa, pt;
    pa.x = f2e4m3(a0.x*32.f) | (f2e4m3(a0.y*32.f) << 8) |
           (f2e4m3(a0.z*32.f) << 16) | (f2e4m3(a0.w*32.f) << 24);
    pa.y = f2e4m3(a1.x*32.f) | (f2e4m3(a1.y*32.f) << 8) |
           (f2e4m3(a1.z*32.f) << 16) | (f2e4m3(a1.w*32.f) << 24);
    pt.x = f2e4m3(t0.x*32.f) | (f2e4m3(t0.y*32.f) << 8) |
           (f2e4m3(t0.z*32.f) << 16) | (f2e4m3(t0.w*32.f) << 24);
    pt.y = f2e4m3(t1.x*32.f) | (f2e4m3(t1.y*32.f) << 8) |
           (f2e4m3(t1.z*32.f) << 16) | (f2e4m3(t1.w*32.f) << 24);

    // K-permuted output position: lane holds k = lane*8..+8.
    // chunk c = lane>>4; g = lane&3; ks = (lane>>2)&3; pos = c*128+g*32+ks*8.
    {
        int c  = lane >> 4;
        int gq = lane & 3;
        int ks = (lane >> 2) & 3;
        size_t opos = (size_t)row * DDIM + c * 128 + gq * 32 + ks * 8;
        *(uint2*)(Aq + opos) = pa;
        *(uint2*)(Bq + opos) = pt;
    }

    #pragma unroll
    for (int m = 1; m < 64; m <<= 1) {
        sa += __shfl_xor(sa, m);
        st += __shfl_xor(st, m);
        dt += __shfl_xor(dt, m);
    }
    if (lane == 0) {
        a2[row] = sa;
        b2[row] = st;
        float a2c  = fminf(sa, 1.0f - EPSF);
        float b2c  = fminf(st, 1.0f - EPSF);
        float diff = sa + st - 2.0f * dt;
        float den  = fmaxf((1.0f - a2c) * (1.0f - b2c), EPSF);
        float arg  = fmaxf(1.0f + 2.0f * diff / den, 1.0f + EPSF);
        diag[row]  = -logf(arg + sqrtf(arg * arg - 1.0f));
    }
}

// 128x128 MFMA GEMM (A@B^T) in fp8, 8 waves (wm=w>>2, wn=w&3), wave-out 64x32.
// BK=128 -> 4 K-steps; 2-buffer prefetch-1 pipeline (R8-proven structure).
__global__ __launch_bounds__(512, 4) void hyper_gemm(
    const unsigned char* __restrict__ A, const unsigned char* __restrict__ B,
    const float* __restrict__ a2, const float* __restrict__ b2,
    float* __restrict__ rowsum, float* __restrict__ colsum) {

    __shared__ char lds[2 * LDSBUF];   // [buf][A 16K | B 16K]

    const int tid  = threadIdx.x;
    const int lane = tid & 63;
    const int w    = tid >> 6;         // 0..7
    const int wm   = w >> 2;           // 0..1
    const int wn   = w & 3;            // 0..3

    // XCD swizzle (round-5 proven): 8 consecutive dispatch slots on one XCD
    // share a B-panel with 8 different A-panels.
    const int bid = blockIdx.x;
    const int idx = bid >> 3;
    const int by  = (bid & 7) * 8 + (idx & 7);
    const int bx  = idx >> 3;
    const int i0 = by * BM;
    const int j0 = bx * BN;

    const int g  = lane >> 4;          // 0..3
    const int cl = lane & 15;          // 0..15

    // ---- staging: wave w stages rows [16w,16w+16) of A and B as 2 chunks of
    // 8 rows (64 lanes x 16B = 1KB/chunk, row = 128B). Linear LDS dest; global
    // 16B-chunk index pre-swizzled: cp = (lane&7) ^ srow ^ ((c&1)<<2)
    // (rule #21: the read side applies the same function).
    const int srow = lane >> 3;                    // 0..7 within chunk
    const unsigned char* aP[2]; const unsigned char* bP[2]; int ldsOff[2];
    #pragma unroll
    for (int c = 0; c < 2; ++c) {
        int row  = w * 16 + c * 8 + srow;
        int cp   = (lane & 7) ^ srow ^ ((c & 1) << 2);   // swizzled 16B chunk
        aP[c] = A + (size_t)(i0 + row) * DDIM + cp * 16;
        bP[c] = B + (size_t)(j0 + row) * DDIM + cp * 16;
        ldsOff[c] = w * 2048 + c * 1024;
    }

    // ---- fragment ds_read_b128 byte offsets: lane (g,cl), frag row r:
    // 32 operand bytes at chunks G=2g, 2g+1; LDS slot = G ^ (r&7) ^ ((r>>3&1)<<2).
    // addr = r*128 + ((g*32 + h*16) ^ ((r&7)<<4) ^ (((r>>3)&1)<<6)); B at +16384.
    int addrA[4][2], addrB[2][2];
    #pragma unroll
    for (int mi = 0; mi < 4; ++mi) {
        int row = wm * 64 + mi * 16 + cl;
        int s = ((row & 7) << 4) ^ (((row >> 3) & 1) << 6);
        #pragma unroll
        for (int h = 0; h < 2; ++h)
            addrA[mi][h] = row * 128 + ((g * 32 + h * 16) ^ s);
    }
    #pragma unroll
    for (int ni = 0; ni < 2; ++ni) {
        int row = wn * 32 + ni * 16 + cl;
        int s = ((row & 7) << 4) ^ (((row >> 3) & 1) << 6);
        #pragma unroll
        for (int h = 0; h < 2; ++h)
            addrB[ni][h] = 16384 + row * 128 + ((g * 32 + h * 16) ^ s);
    }

    f32x4 acc[4][2];
    #pragma unroll
    for (int mi = 0; mi < 4; ++mi)
        #pragma unroll
        for (int ni = 0; ni < 2; ++ni)
            acc[mi][ni] = (f32x4)0.0f;

#define STAGE(buf, t)                                                     \
    do {                                                                  \
        _Pragma("unroll")                                                 \
        for (int c = 0; c < 2; ++c) {                                     \
            GLOAD_LDS16(aP[c] + (t) * BK,                                 \
                        lds + (buf) * LDSBUF + ldsOff[c]);                \
            GLOAD_LDS16(bP[c] + (t) * BK,                                 \
                        lds + (buf) * LDSBUF + 16384 + ldsOff[c]);        \
        }                                                                 \
    } while (0)

// Per half h: one ds_read_b128 per fragment-row (i64x2), whose two longs are
// the MFMA operands for k-slices 2h and 2h+1. setprio(1) around MFMA cluster.
#define COMPUTE(buf)                                                      \
    do {                                                                  \
        _Pragma("unroll")                                                 \
        for (int h = 0; h < 2; ++h) {                                     \
            i64x2 va[4], vb[2];                                           \
            _Pragma("unroll")                                             \
            for (int mi = 0; mi < 4; ++mi)                                \
                va[mi] = *(const i64x2*)(lds + (buf) * LDSBUF + addrA[mi][h]); \
            _Pragma("unroll")                                             \
            for (int ni = 0; ni < 2; ++ni)                                \
                vb[ni] = *(const i64x2*)(lds + (buf) * LDSBUF + addrB[ni][h]); \
            __builtin_amdgcn_s_setprio(1);                                \
            _Pragma("unroll")                                             \
            for (int half = 0; half < 2; ++half)                          \
                _Pragma("unroll")                                         \
                for (int mi = 0; mi < 4; ++mi)                            \
                    _Pragma("unroll")                                     \
                    for (int ni = 0; ni < 2; ++ni)                        \
                        acc[mi][ni] = __builtin_amdgcn_mfma_f32_16x16x32_fp8_fp8( \
                            va[mi][half], vb[ni][half], acc[mi][ni], 0, 0, 0);    \
            __builtin_amdgcn_s_setprio(0);                                \
        }                                                                 \
    } while (0)

    STAGE(0, 0);
    __syncthreads();                       // tile 0 resident
    #pragma unroll
    for (int t = 0; t < NT; ++t) {
        if (t + 1 < NT) STAGE((t + 1) & 1, t + 1);   // prefetch next tile
        COMPUTE(t & 1);
        if (t + 1 < NT) __syncthreads();   // drains prefetch + lds reads
    }
#undef STAGE
#undef COMPUTE

    // ---- epilogue: e = arg - sqrt(arg^2-1); accumulate row/col partials.
    float B2c[2], fb[2];
    #pragma unroll
    for (int ni = 0; ni < 2; ++ni) {
        float B2 = b2[j0 + wn * 32 + ni * 16 + cl];
        B2c[ni] = B2;
        fb[ni] = __builtin_amdgcn_rcpf(1.0f - fminf(B2, 1.0f - EPSF));
    }

    float cp[2] = {0.f, 0.f};
    #pragma unroll
    for (int mi = 0; mi < 4; ++mi) {
        #pragma unroll
        for (int reg = 0; reg < 4; ++reg) {
            int   gi  = i0 + wm * 64 + mi * 16 + g * 4 + reg;
            float A2  = a2[gi];
            float fa  = 2.0f * __builtin_amdgcn_rcpf(1.0f - fminf(A2, 1.0f - EPSF));
            float rsum = 0.f;
            #pragma unroll
            for (int ni = 0; ni < 2; ++ni) {
                float dot  = acc[mi][ni][reg];
                float diff = fmaf(-2.0f * DOT_SCALE, dot, A2 + B2c[ni]);
                float arg  = fmaf(diff * fa, fb[ni], 1.0f);
                arg = fmaxf(arg, 1.0f);
                float sq = sqrtf(fmaf(arg, arg, -1.0f));
                float e  = arg - sq;      // exp(-arccosh(arg)), exact
                rsum += e;
                cp[ni] += e;
            }
            float v = rsum;
            v += __shfl_xor(v, 1); v += __shfl_xor(v, 2);
            v += __shfl_xor(v, 4); v += __shfl_xor(v, 8);
            if (cl == 0) atomicAdd(&rowsum[gi], v);
        }
    }
    #pragma unroll
    for (int ni = 0; ni < 2; ++ni) {
        float v = cp[ni];
        v += __shfl_xor(v, 16); v += __shfl_xor(v, 32);
        if (g == 0) atomicAdd(&colsum[j0 + wn * 32 + ni * 16 + cl], v);
    }
}

// Single block, direct write to out[0].
__global__ __launch_bounds__(1024) void finalize(const float* __restrict__ rowsum,
                                                 const float* __restrict__ colsum,
                                                 const float* __restrict__ diag,
                                                 float* __restrict__ out) {
    float s = 0.f;
    for (int i = threadIdx.x; i < NROWS; i += 1024)
        s += logf(rowsum[i]) + logf(colsum[i]) - 2.0f * diag[i];
    __shared__ float red[16];
    int lane = threadIdx.x & 63, wv = threadIdx.x >> 6;
    #pragma unroll
    for (int m = 1; m < 64; m <<= 1) s += __shfl_xor(s, m);
    if (lane == 0) red[wv] = s;
    __syncthreads();
    if (threadIdx.x == 0) {
        float t = 0.f;
        #pragma unroll
        for (int k = 0; k < 16; ++k) t += red[k];
        out[0] = t / (2.0f * NROWS);
    }
}

extern "C" void kernel_launch(void* const* d_in, const int* in_sizes, int n_in,
                              void* d_out, int out_size, void* d_ws, size_t ws_size,
                              hipStream_t stream) {
    const float* audio = (const float*)d_in[0];
    const float* text  = (const float*)d_in[1];
    // labels (d_in[2]) are arange(N) -> diagonal; not needed.
    float* out = (float*)d_out;

    char* ws = (char*)d_ws;
    const size_t BF = (size_t)NROWS * DDIM;   // 4 MiB per fp8 matrix
    unsigned char* Aq = (unsigned char*)ws;
    unsigned char* Bq = (unsigned char*)(ws + BF);
    float* a2     = (float*)(ws + 2 * BF);
    float* b2     = a2 + NROWS;
    float* rowsum = b2 + NROWS;
    float* colsum = rowsum + NROWS;
    float* diag   = colsum + NROWS;

    convert_norms<<<NROWS / 4, 256, 0, stream>>>(audio, text, Aq, Bq, a2, b2, diag, rowsum);
    hyper_gemm<<<(NROWS / BM) * (NROWS / BN), 512, 0, stream>>>(Aq, Bq, a2, b2, rowsum, colsum);
    finalize<<<1, 1024, 0, stream>>>(rowsum, colsum, diag, out);
}